// Round 7
// baseline (241.215 us; speedup 1.0000x reference)
//
#include <hip/hip_runtime.h>

// MMSE-PIC detector: B=32768, M=16, S=8, QAM16 Gray, 2 iterations.
// Round 7: packed-fp32 math. Complex arithmetic written as ext_vector float2
// so ISel emits v_pk_fma_f32/v_pk_mul_f32 (VOP3P, 2x f32 per issue slot):
//  - elimination row update: 4 FMA -> 2 pk_fma (+1 pk_mul for multiplier)
//  - Gram/y_mf: deferred combine (G1 += a.x*x; G2 += a.y*x) -> 2 pk_fma/term
// Inner register GJ and demap stay scalar (small share, proven correct).

#define EPS_F 1e-4f
#define INV_SQRT10 0.31622776601683794f
#define WSYNC() __builtin_amdgcn_wave_barrier()

typedef float v2f __attribute__((ext_vector_type(2)));

__device__ __forceinline__ float rcpf(float x) { return __builtin_amdgcn_rcpf(x); }
__device__ __forceinline__ float rsqf(float x) { return __builtin_amdgcn_rsqf(x); }
__device__ __forceinline__ float rdlane(float v, int l) {
    return __uint_as_float(__builtin_amdgcn_readlane(__float_as_uint(v), l));
}
template<int OFF>
__device__ __forceinline__ float swzf(float v) {
    return __uint_as_float(__builtin_amdgcn_ds_swizzle(__float_as_uint(v), OFF));
}
// xor-butterfly swizzle patterns (BitMode: offset = xor<<10 | or<<5 | and)
#define SWX1 0x041F
#define SWX2 0x081F
#define SWX4 0x101F

__device__ __forceinline__ float pt_re(int p) {
    return (1.0f - 2.0f * (float)((p >> 3) & 1)) * (1.0f + 2.0f * (float)((p >> 1) & 1)) * INV_SQRT10;
}
__device__ __forceinline__ float pt_im(int p) {
    return (1.0f - 2.0f * (float)((p >> 2) & 1)) * (1.0f + 2.0f * (float)(p & 1)) * INV_SQRT10;
}

__global__ __launch_bounds__(128, 4)
void mmse_pic_kernel(const float* __restrict__ y_re, const float* __restrict__ y_im,
                     const float* __restrict__ h_re, const float* __restrict__ h_im,
                     const float* __restrict__ prior,
                     const float* __restrict__ s_re, const float* __restrict__ s_im,
                     float* __restrict__ out)
{
    const int lane = threadIdx.x & 63;
    const int w    = threadIdx.x >> 6;            // wave id in block = sub-batch
    const int b    = blockIdx.x * 2 + w;
    const size_t bs = (size_t)b;

    __shared__ v2f   Sc[2][16][28];   // [S(0-15) | h(16-23) | y(24)] -> W after elim+scale
    __shared__ v2f   xc_[2][8];
    __shared__ v2f   ymc_[2][8];
    __shared__ float vx_[2][8], ne_[2][8];
    __shared__ float lsig[2][64];
    __shared__ float logit_[2][8][20];
    __shared__ float llrD_[2][8][4];

    // ---- load (vectorized, interleave re/im into float2) ----
    {
        const float4* pr4 = (const float4*)(s_re + bs * 256);
        const float4* pi4 = (const float4*)(s_im + bs * 256);
        float4 vr = pr4[lane], vi = pi4[lane];
        int r = lane >> 2, c0 = (lane & 3) << 2;
        Sc[w][r][c0+0] = (v2f){vr.x, vi.x};
        Sc[w][r][c0+1] = (v2f){vr.y, vi.y};
        Sc[w][r][c0+2] = (v2f){vr.z, vi.z};
        Sc[w][r][c0+3] = (v2f){vr.w, vi.w};
        if (lane < 32) {
            const float4* hr4 = (const float4*)(h_re + bs * 128);
            const float4* hi4 = (const float4*)(h_im + bs * 128);
            float4 hr = hr4[lane], hi = hi4[lane];
            int row = lane >> 1, col = 16 + ((lane & 1) << 2);
            Sc[w][row][col+0] = (v2f){hr.x, hi.x};
            Sc[w][row][col+1] = (v2f){hr.y, hi.y};
            Sc[w][row][col+2] = (v2f){hr.z, hi.z};
            Sc[w][row][col+3] = (v2f){hr.w, hi.w};
        }
        if (lane < 16) Sc[w][lane][24] = (v2f){y_re[bs*16+lane], y_im[bs*16+lane]};
        if (lane < 32) ((float*)llrD_[w])[lane] = prior[bs*32 + lane];
    }
    WSYNC();

    // ---- forward-only unnormalized elimination on [S | h y] (fully unrolled,
    //      packed-f32 complex update: a -= mv.x*rk + mv.y*rk_alt) ----
    {
        const int j0 = lane & 15;
        const int r4 = lane >> 4;
        #pragma unroll
        for (int k = 0; k < 15; ++k) {
            float invd = rcpf(Sc[w][k][k].x);
            int j1 = k + 1 + j0, j2 = j1 + 16;
            v2f rk0 = (v2f){0.f, 0.f}, rk1 = (v2f){0.f, 0.f};
            if (j1 < 25) rk0 = Sc[w][k][j1];
            const bool blk2 = (k < 8);
            if (blk2 && j2 < 25) rk1 = Sc[w][k][j2];
            v2f rk0A = (v2f){-rk0.y, rk0.x};
            v2f rk1A = (v2f){-rk1.y, rk1.x};
            const int pmin = (k + 1) >> 2;          // compile-time per unrolled k
            #pragma unroll
            for (int p = 0; p < 4; ++p) {
                if (p < pmin) continue;
                int i = (p << 2) + r4;
                v2f aik = Sc[w][i][k];
                v2f mv = aik * invd;                 // v_pk_mul
                if (i <= k) mv = (v2f){0.f, 0.f};
                if (j1 < 25) {
                    v2f a = Sc[w][i][j1];
                    a -= mv.x * rk0;                 // v_pk_fma
                    a -= mv.y * rk0A;                // v_pk_fma
                    Sc[w][i][j1] = a;
                }
                if (blk2 && j2 < 25) {
                    v2f a = Sc[w][i][j2];
                    a -= mv.x * rk1;
                    a -= mv.y * rk1A;
                    Sc[w][i][j2] = a;
                }
            }
            WSYNC();
        }
    }
    // ---- scale RHS rows by rsqrt(d_m): W = D^-1/2 L^-1 [h|y] (= whitened) ----
    {
        int r2 = lane >> 2, c = lane & 3;
        float irs = rsqf(Sc[w][r2][r2].x);
        Sc[w][r2][16 + c] = Sc[w][r2][16 + c] * irs;
        Sc[w][r2][20 + c] = Sc[w][r2][20 + c] * irs;
        if (c == 0) Sc[w][r2][24] = Sc[w][r2][24] * irs;
    }
    WSYNC();

    // ---- Gram g[i][j] = (Wh^H Wh)[i][j] (1 entry/lane), y_mf = Wh^H Wy ----
    // Deferred combine: G1 += a.x*x, G2 += a.y*x; g = (G1.x+G2.y, G1.y-G2.x)
    const int s = lane >> 3, u = lane & 7;
    v2f G1 = (v2f){0.f, 0.f}, G2 = (v2f){0.f, 0.f};
    v2f Y1 = (v2f){0.f, 0.f}, Y2 = (v2f){0.f, 0.f};
    #pragma unroll
    for (int m = 0; m < 16; ++m) {
        v2f a  = Sc[w][m][16 + s];
        v2f x  = Sc[w][m][16 + u];
        v2f xy = Sc[w][m][24];
        G1 += a.x * x;   G2 += a.y * x;
        Y1 += a.x * xy;  Y2 += a.y * xy;
    }
    const float g_re = G1.x + G2.y;
    const float g_im = G1.y - G2.x;
    if (u == 0) ymc_[w][s] = (v2f){Y1.x + Y2.y, Y1.y - Y2.x};
    WSYNC();

    const float pr = pt_re(u), pi2 = pt_im(u), pe = pr*pr + pi2*pi2;  // pt(u+8) = (-pr, pi2)
    float llr_a_reg = 0.f;

    for (int it = 0; it < 2; ++it) {
        // log-sigmoid table: one distinct value per lane
        {
            int ts = lane >> 3, tk = (lane >> 1) & 3, sg = lane & 1;
            float v = llrD_[w][ts][tk];
            float x = sg ? v : -v;
            lsig[w][lane] = fminf(x, 0.f) - __logf(1.0f + __expf(-fabsf(x)));
        }
        if (lane < 32) llr_a_reg = ((float*)llrD_[w])[lane];
        WSYNC();
        // symbol logits for p=u (l0) and p=u+8 (l1), in registers
        int base = s << 3;
        float lc = lsig[w][base | 2 | ((u >> 2) & 1)]
                 + lsig[w][base | 4 | ((u >> 1) & 1)]
                 + lsig[w][base | 6 | (u & 1)];
        float l0 = lc + lsig[w][base];
        float l1 = lc + lsig[w][base | 1];
        // moments: swizzle-butterfly over the 8 lanes of stream s
        {
            float mx = fmaxf(l0, l1);
            mx = fmaxf(mx, swzf<SWX1>(mx));
            mx = fmaxf(mx, swzf<SWX2>(mx));
            mx = fmaxf(mx, swzf<SWX4>(mx));
            float w0 = __expf(l0 - mx), w1 = __expf(l1 - mx);
            float a = w0 + w1, dw = w0 - w1;
            float se = a, mr = dw * pr, mi = a * pi2, e2 = a * pe;
            se += swzf<SWX1>(se); mr += swzf<SWX1>(mr); mi += swzf<SWX1>(mi); e2 += swzf<SWX1>(e2);
            se += swzf<SWX2>(se); mr += swzf<SWX2>(mr); mi += swzf<SWX2>(mi); e2 += swzf<SWX2>(e2);
            se += swzf<SWX4>(se); mr += swzf<SWX4>(mr); mi += swzf<SWX4>(mi); e2 += swzf<SWX4>(e2);
            if (u == 0) {
                float inv = rcpf(se);
                float mxr = mr*inv, mxi = mi*inv;
                xc_[w][s] = (v2f){mxr, mxi};
                vx_[w][s] = e2*inv - (mxr*mxr + mxi*mxi);
            }
        }
        WSYNC();
        // setup: b_i = y_mf[i] - (g x)_i, A = I + g diag(var), C = g
        v2f xj = xc_[w][u];
        float vj = vx_[w][u];
        float tr = g_re*xj.x - g_im*xj.y;
        float ti = g_re*xj.y + g_im*xj.x;
        tr += swzf<SWX1>(tr); ti += swzf<SWX1>(ti);
        tr += swzf<SWX2>(tr); ti += swzf<SWX2>(ti);
        tr += swzf<SWX4>(tr); ti += swzf<SWX4>(ti);
        v2f ym = ymc_[w][s];
        float br_ = ym.x - tr, bi_ = ym.y - ti;
        float Ar = g_re*vj + ((s == u) ? 1.f : 0.f);
        float Ai = g_im*vj;
        float Cr = g_re, Ci = g_im;
        // inner unnormalized GJ on [A | b | C]: registers; pivot via v_readlane
        // (uniform), multiplier bcast via ds_swizzle (src=(L&0x38)|K), row bcast
        // via bpermute.
        #define GJ_STEP(K) { \
            float pvr = rdlane(Ar, (K)*9), pvi = rdlane(Ai, (K)*9); \
            int rowsrc = ((K)<<3)|u; \
            float rAr = __shfl(Ar, rowsrc), rAi = __shfl(Ai, rowsrc); \
            float rCr = __shfl(Cr, rowsrc), rCi = __shfl(Ci, rowsrc); \
            float rbr = __shfl(br_, rowsrc), rbi = __shfl(bi_, rowsrc); \
            float cAr = swzf<(((K)<<5)|0x18)>(Ar), cAi = swzf<(((K)<<5)|0x18)>(Ai); \
            float id2 = rcpf(pvr*pvr + pvi*pvi); \
            float ipr2 = pvr*id2, ipi2 = -pvi*id2; \
            float mr2 = cAr*ipr2 - cAi*ipi2; \
            float mi2 = cAr*ipi2 + cAi*ipr2; \
            if (s == (K)) { mr2 = 0.f; mi2 = 0.f; } \
            Ar  -= mr2*rAr - mi2*rAi;  Ai  -= mr2*rAi + mi2*rAr; \
            Cr  -= mr2*rCr - mi2*rCi;  Ci  -= mr2*rCi + mi2*rCr; \
            br_ -= mr2*rbr - mi2*rbi;  bi_ -= mr2*rbi + mi2*rbr; }
        GJ_STEP(0) GJ_STEP(1) GJ_STEP(2) GJ_STEP(3)
        GJ_STEP(4) GJ_STEP(5) GJ_STEP(6) GJ_STEP(7)
        #undef GJ_STEP
        // extraction on diagonal lanes: z = (w + Cii*x)/mu, no_eff
        if (s == u) {
            float id3 = rcpf(Ar*Ar + Ai*Ai);
            float ipr3 = Ar*id3, ipi3 = -Ai*id3;
            float wr = br_*ipr3 - bi_*ipi3;
            float wi = br_*ipi3 + bi_*ipr3;
            float ccr = Cr*ipr3 - Ci*ipi3;
            float cci = Cr*ipi3 + Ci*ipr3;
            float mu = ccr;
            float im = rcpf(mu);
            float zr = (wr + ccr*xj.x - cci*xj.y) * im;
            float zi = (wi + ccr*xj.y + cci*xj.x) * im;
            xc_[w][s] = (v2f){zr, zi};
            ne_[w][s] = fmaxf(1.f - vx_[w][s]*mu, EPS_F) * im;
        }
        WSYNC();
        // demap: 2 points per lane
        {
            v2f xh = xc_[w][s];
            float idn = rcpf(ne_[w][s]);
            float dr0 = xh.x - pr, dr1 = xh.x + pr, di = xh.y - pi2;
            logit_[w][s][u]     = l0 - (dr0*dr0 + di*di) * idn;
            logit_[w][s][u + 8] = l1 - (dr1*dr1 + di*di) * idn;
        }
        WSYNC();
        // max-log LLR: lane = (s2, bit kb, half); max over 8 matching points
        {
            int s2 = lane >> 3, kb = (lane >> 1) & 3, half = lane & 1;
            int bitpos = 3 - kb;
            float m = -1e30f;
            #pragma unroll
            for (int q = 0; q < 8; ++q) {
                int low  = q & ((1 << bitpos) - 1);
                int high = (q >> bitpos) << (bitpos + 1);
                int p = high | (half << bitpos) | low;
                m = fmaxf(m, logit_[w][s2][p]);
            }
            float other = swzf<SWX1>(m);
            if (half == 1) llrD_[w][s2][kb] = m - other;   // l1 - l0
        }
        WSYNC();
    }

    if (lane < 32) out[bs*32 + lane] = ((float*)llrD_[w])[lane] - llr_a_reg;
}

extern "C" void kernel_launch(void* const* d_in, const int* in_sizes, int n_in,
                              void* d_out, int out_size, void* d_ws, size_t ws_size,
                              hipStream_t stream) {
    const float* y_re  = (const float*)d_in[0];
    const float* y_im  = (const float*)d_in[1];
    const float* h_re  = (const float*)d_in[2];
    const float* h_im  = (const float*)d_in[3];
    const float* prior = (const float*)d_in[4];
    const float* s_re  = (const float*)d_in[5];
    const float* s_im  = (const float*)d_in[6];
    float* out = (float*)d_out;

    const int B = in_sizes[0] / 16;
    mmse_pic_kernel<<<dim3(B / 2), dim3(128), 0, stream>>>(
        y_re, y_im, h_re, h_im, prior, s_re, s_im, out);
}